// Round 9
// baseline (197.839 us; speedup 1.0000x reference)
//
#include <hip/hip_runtime.h>
#include <hip/hip_bf16.h>
#include <cstdint>
#include <cstddef>

// Shapes: b=8, n=8, p=q=64, x=32, y=32, d=8  -> xyd = x*256+y*8+d in [0,8192)
// Q,K,V: [bn=64][64][8192] fp32.  out: [b][p][xyd][n] fp32 (transposed).
// scores[bn][p][q] = dot_k(Q,K)/1024 -> softmax over q -> out = attn @ V.
//
// R8 lesson: 64-row x 1KB-piece strided reads cap at ~2.3 TB/s no matter the
// issue structure. So: repack Q,K -> bf16 tiles with CONTIGUOUS streaming
// (repack written into d_out, which pv overwrites later), then qk reads one
// contiguous 64 KB tile-pair per block.

typedef __attribute__((ext_vector_type(4))) float f32x4;
typedef __attribute__((ext_vector_type(8))) short bf16x8;
typedef __attribute__((ext_vector_type(4))) short shortx4;

__device__ __forceinline__ unsigned short f2bf(float x) {
    unsigned int u = __builtin_bit_cast(unsigned int, x);
    u += 0x7FFFu + ((u >> 16) & 1u);     // RTNE
    return (unsigned short)(u >> 16);
}

__device__ __forceinline__ bf16x8 pack8(float4 lo, float4 hi) {
    bf16x8 f;
    f[0] = (short)f2bf(lo.x); f[1] = (short)f2bf(lo.y);
    f[2] = (short)f2bf(lo.z); f[3] = (short)f2bf(lo.w);
    f[4] = (short)f2bf(hi.x); f[5] = (short)f2bf(hi.y);
    f[6] = (short)f2bf(hi.z); f[7] = (short)f2bf(hi.w);
    return f;
}

// async global -> LDS, 16 bytes per lane (dest wave-linear: base+lane*16)
__device__ __forceinline__ void gload16(const float* g,
    __attribute__((address_space(3))) float* l)
{
    __builtin_amdgcn_global_load_lds(
        (const __attribute__((address_space(1))) unsigned int*)(uintptr_t)g,
        (__attribute__((address_space(3))) unsigned int*)l, 16, 0, 0);
}

// ---------------- Kernel R: repack Q,K -> bf16 swizzled tiles ----------------
// grid (bn=64, rg=8, qk=2), 256 threads. Block reads 8 FULL contiguous rows
// (8 x 32 KB), writes tiles [bn][ch=32][qk=2][row=64][col=256] bf16 with the
// 16B-slot XOR swizzle (slot' = slot ^ (row&7)) baked into the layout.
__global__ __launch_bounds__(256) void repack_kernel(
    const float* __restrict__ Q, const float* __restrict__ K,
    unsigned short* __restrict__ t)
{
    const int bn  = blockIdx.x;
    const int rg  = blockIdx.y;
    const int qk  = blockIdx.z;
    const int tid = threadIdx.x;
    const float* src = (qk ? K : Q) + (size_t)bn * 64 * 8192;
    // per-(bn,ch,qk) tile = 16384 shorts; ch stride = 2 tiles
    unsigned short* dstb = t + ((size_t)bn * 64 + qk) * 16384;

    const int ch = tid >> 3;            // 32 floats/thread -> ch = tid*32/256
    const int s0 = (tid & 7) * 4;       // first 16B slot within row

    #pragma unroll 1
    for (int r = 0; r < 8; ++r) {
        const int row = rg * 8 + r;
        const float4* p = (const float4*)(src + (size_t)row * 8192 + tid * 32);
        float4 v[8];
        #pragma unroll
        for (int j = 0; j < 8; ++j) v[j] = p[j];
        unsigned short* trow = dstb + (size_t)ch * 2 * 16384 + row * 256;
        #pragma unroll
        for (int j2 = 0; j2 < 4; ++j2) {
            const int s = (s0 + j2) ^ (row & 7);
            *(bf16x8*)(trow + s * 8) = pack8(v[2 * j2], v[2 * j2 + 1]);
        }
    }
}

// ---------------- Kernel A: partial QK^T via bf16 MFMA, contiguous tiles ----
// grid (bn=64, ch=32), 1024 threads = 16 waves. ONE contiguous 64 KB
// global_load_lds burst (tile-pair), then 8 MFMA k-steps (R8-proven loop).
// partial[ch][bn][p][q]
__global__ __launch_bounds__(1024) void qk_mfma_kernel(
    const unsigned short* __restrict__ t, float* __restrict__ partial)
{
    __shared__ unsigned short tile[2][16384];   // [Q/K][row*256+swzcol] 64 KiB

    const int bn   = blockIdx.x;
    const int ch   = blockIdx.y;
    const int tid  = threadIdx.x;
    const int w    = tid >> 6;
    const int lane = tid & 63;
    const int frow = lane & 15;
    const int kg   = lane >> 4;

    const float* src = (const float*)(t + ((size_t)bn * 32 + ch) * 2 * 16384);
    auto l3 = (__attribute__((address_space(3))) float*)(uintptr_t)&tile[0][0];

    // 64 KB = 64 wave-chunks of 1 KB; wave w issues 4 (linear dest)
    #pragma unroll
    for (int i = 0; i < 4; ++i) {
        const int c = w * 4 + i;
        gload16(src + c * 256 + lane * 4, l3 + c * 256 + lane * 4);
    }
    __syncthreads();

    f32x4 acc = (f32x4)(0.f);
    const int arow = (w >> 2) * 16 + frow;   // p-row
    const int brow = (w & 3) * 16 + frow;    // q-row
    const unsigned short* Qs = tile[0];
    const unsigned short* Ks = tile[1];
    #pragma unroll
    for (int ks = 0; ks < 8; ++ks) {
        const bf16x8 a = *(const bf16x8*)(Qs + arow * 256 +
                            (((ks * 4 + kg) ^ (arow & 7)) * 8));
        const bf16x8 b = *(const bf16x8*)(Ks + brow * 256 +
                            (((ks * 4 + kg) ^ (brow & 7)) * 8));
        acc = __builtin_amdgcn_mfma_f32_16x16x32_bf16(a, b, acc, 0, 0, 0);
    }

    // D layout: col = lane&15 (q), row = kg*4 + r (p)
    float* pb = partial + ((size_t)ch * 64 + bn) * 4096;
    const int p0 = (w >> 2) * 16 + kg * 4;
    const int q0 = (w & 3) * 16 + frow;
    #pragma unroll
    for (int r = 0; r < 4; ++r)
        pb[(size_t)(p0 + r) * 64 + q0] = acc[r];
}

// ---------------- Kernel B: reduce partials + softmax (unchanged) ----------------
__global__ __launch_bounds__(256) void softmax_kernel(
    float* __restrict__ ws, const unsigned char* __restrict__ mask, int kchunks)
{
    const int row  = blockIdx.x * 4 + (threadIdx.x >> 6);
    const int q    = threadIdx.x & 63;
    float s = 0.f;
    for (int c = 0; c < kchunks; ++c)
        s += ws[((size_t)c * 4096 + row) * 64 + q];
    s *= (1.0f / 1024.0f);
    const int b = row >> 9;
    if (mask[b * 64 + q]) s = -__builtin_inff();
    float m = s;
    #pragma unroll
    for (int off = 32; off; off >>= 1) m = fmaxf(m, __shfl_xor(m, off));
    const float e = __expf(s - m);
    float sum = e;
    #pragma unroll
    for (int off = 32; off; off >>= 1) sum += __shfl_xor(sum, off);
    ws[(size_t)row * 64 + q] = e / sum;
}

// ---------------- Kernel C: PV via bf16 MFMA (unchanged, proven) ----------------
__global__ __launch_bounds__(512, 2) void pv_mfma_kernel(
    const float* __restrict__ V, const float* __restrict__ attn,
    float* __restrict__ out)
{
    __shared__ unsigned char smem[65536];   // phase 1: vt[8][64][64] bf16; phase 2: ob fp32

    const int b     = blockIdx.y;
    const int chunk = blockIdx.x;
    const int tid   = threadIdx.x;
    const int w     = tid >> 6;           // wave = n
    const int lane  = tid & 63;

    const float* Vb = V    + (size_t)(b * 8 + w) * 64 * 8192 + (size_t)chunk * 64;
    const float* Ab = attn + (size_t)(b * 8 + w) * 4096;

    unsigned short* vtn = (unsigned short*)smem + w * 4096;   // this wave's V^T tile

    // ---- stage V chunk -> LDS transposed bf16, swizzled ----
    const int c  = lane >> 2;
    const int qg = lane & 3;
    #pragma unroll
    for (int s = 0; s < 4; ++s) {
        const int q0 = s * 16 + qg * 4;
        const float4 r0 = *(const float4*)&Vb[(size_t)(q0 + 0) * 8192 + c * 4];
        const float4 r1 = *(const float4*)&Vb[(size_t)(q0 + 1) * 8192 + c * 4];
        const float4 r2 = *(const float4*)&Vb[(size_t)(q0 + 2) * 8192 + c * 4];
        const float4 r3 = *(const float4*)&Vb[(size_t)(q0 + 3) * 8192 + c * 4];
        const float v0[4] = {r0.x, r0.y, r0.z, r0.w};
        const float v1[4] = {r1.x, r1.y, r1.z, r1.w};
        const float v2[4] = {r2.x, r2.y, r2.z, r2.w};
        const float v3[4] = {r3.x, r3.y, r3.z, r3.w};
        #pragma unroll
        for (int cc = 0; cc < 4; ++cc) {
            const int row = c * 4 + cc;       // xc within chunk
            shortx4 pk;
            pk.x = (short)f2bf(v0[cc]);
            pk.y = (short)f2bf(v1[cc]);
            pk.z = (short)f2bf(v2[cc]);
            pk.w = (short)f2bf(v3[cc]);
            const int soff = row * 64 + (q0 ^ ((row & 7) << 3) ^ (((row >> 3) & 3) << 4));
            *(shortx4*)(vtn + soff) = pk;
        }
    }

    // ---- A fragments: attn rows, bf16 ----
    const int arow = lane & 15;
    const int q0a  = (lane >> 4) * 8;
    bf16x8 afrag[4][2];
    #pragma unroll
    for (int mt = 0; mt < 4; ++mt) {
        #pragma unroll
        for (int ks = 0; ks < 2; ++ks) {
            const float* ap = Ab + (mt * 16 + arow) * 64 + ks * 32 + q0a;
            const float4 lo = *(const float4*)ap;
            const float4 hi = *(const float4*)(ap + 4);
            afrag[mt][ks] = pack8(lo, hi);
        }
    }

    // ---- MFMA compute ----
    f32x4 acc[4][4];
    #pragma unroll
    for (int mt = 0; mt < 4; ++mt)
        #pragma unroll
        for (int nt = 0; nt < 4; ++nt)
            acc[mt][nt] = (f32x4)(0.f);

    const int bcol = lane & 15;
    const int q0b  = (lane >> 4) * 8;
    #pragma unroll
    for (int nt = 0; nt < 4; ++nt) {
        bf16x8 bfr[2];
        #pragma unroll
        for (int ks = 0; ks < 2; ++ks) {
            const int row  = nt * 16 + bcol;
            const int q0   = ks * 32 + q0b;
            const int soff = row * 64 + (q0 ^ ((row & 7) << 3) ^ (((row >> 3) & 3) << 4));
            bfr[ks] = *(const bf16x8*)(vtn + soff);
        }
        #pragma unroll
        for (int ks = 0; ks < 2; ++ks)
            #pragma unroll
            for (int mt = 0; mt < 4; ++mt)
                acc[mt][nt] = __builtin_amdgcn_mfma_f32_16x16x32_bf16(
                    afrag[mt][ks], bfr[ks], acc[mt][nt], 0, 0, 0);
    }

    // ---- store: D frags -> LDS transpose -> coalesced float4 stores ----
    float* ob = (float*)smem;          // [16 p][64 xc][9 (8n + pad)]
    const int pq = lane >> 4;
    const int pl = tid >> 5;           // 0..15 : p-row for store phase
    const int g  = tid & 31;
    #pragma unroll
    for (int mt = 0; mt < 4; ++mt) {
        __syncthreads();
        #pragma unroll
        for (int nt = 0; nt < 4; ++nt)
            #pragma unroll
            for (int r = 0; r < 4; ++r) {
                const int prow = pq * 4 + r;
                const int xc   = nt * 16 + (lane & 15);
                ob[prow * 576 + xc * 9 + w] = acc[mt][nt][r];
            }
        __syncthreads();
        float* orow = out + (size_t)b * 4194304 + (size_t)(mt * 16 + pl) * 65536
                          + (size_t)chunk * 512;
        #pragma unroll
        for (int u = 0; u < 4; ++u) {
            const int f0 = g * 4 + u * 128;
            float4 vv;
            vv.x = ob[pl * 576 + ((f0 + 0) >> 3) * 9 + ((f0 + 0) & 7)];
            vv.y = ob[pl * 576 + ((f0 + 1) >> 3) * 9 + ((f0 + 1) & 7)];
            vv.z = ob[pl * 576 + ((f0 + 2) >> 3) * 9 + ((f0 + 2) & 7)];
            vv.w = ob[pl * 576 + ((f0 + 3) >> 3) * 9 + ((f0 + 3) & 7)];
            *(float4*)&orow[f0] = vv;
        }
    }
}

extern "C" void kernel_launch(void* const* d_in, const int* in_sizes, int n_in,
                              void* d_out, int out_size, void* d_ws, size_t ws_size,
                              hipStream_t stream)
{
    const float* Q = (const float*)d_in[0];
    const float* K = (const float*)d_in[1];
    const float* V = (const float*)d_in[2];
    const unsigned char* mask = (const unsigned char*)d_in[3];
    float* out = (float*)d_out;
    float* ws  = (float*)d_ws;

    // Repacked bf16 tiles live in d_out (128 MiB, exact fit); pv overwrites
    // d_out only after qk has consumed the tiles (same-stream serial order).
    unsigned short* tiles = (unsigned short*)d_out;

    const int kchunks = 32;   // partial = 32 MiB in ws (proven fits, R8)

    repack_kernel<<<dim3(64, 8, 2), 256, 0, stream>>>(Q, K, tiles);
    qk_mfma_kernel<<<dim3(64, 32), 1024, 0, stream>>>(tiles, ws);
    softmax_kernel<<<1024, 256, 0, stream>>>(ws, mask, kchunks);
    pv_mfma_kernel<<<dim3(128, 8), 512, 0, stream>>>(V, ws, out);
}

// Round 10
// 137.345 us; speedup vs baseline: 1.4404x; 1.4404x over previous
//
#include <hip/hip_runtime.h>
#include <hip/hip_bf16.h>
#include <cstdint>
#include <cstddef>

// Shapes: b=8, n=8, p=q=64, x=32, y=32, d=8  -> xyd = x*256+y*8+d in [0,8192)
// Q,K,V: [bn=64][64][8192] fp32.  out: [b][p][xyd][n] fp32 (transposed).
// scores[bn][p][q] = dot_k(Q,K)/1024 -> softmax over q -> out = attn @ V.
//
// R9 lesson: per-block contiguity doesn't matter; CROSS-BLOCK adjacency does.
// pv (fast) has its column-chunk as fastest blockIdx -> concurrent blocks read
// adjacent pieces of the same rows -> DRAM page hits. All qk variants had bn
// fastest (concurrent streams MBs apart) -> ~2.3 TB/s page-miss wall.
// This round: R8 kernel, grid order swapped to (ch fastest, bn slowest).

typedef __attribute__((ext_vector_type(4))) float f32x4;
typedef __attribute__((ext_vector_type(8))) short bf16x8;
typedef __attribute__((ext_vector_type(4))) short shortx4;

__device__ __forceinline__ unsigned short f2bf(float x) {
    unsigned int u = __builtin_bit_cast(unsigned int, x);
    u += 0x7FFFu + ((u >> 16) & 1u);     // RTNE
    return (unsigned short)(u >> 16);
}

__device__ __forceinline__ bf16x8 pack8(float4 lo, float4 hi) {
    bf16x8 f;
    f[0] = (short)f2bf(lo.x); f[1] = (short)f2bf(lo.y);
    f[2] = (short)f2bf(lo.z); f[3] = (short)f2bf(lo.w);
    f[4] = (short)f2bf(hi.x); f[5] = (short)f2bf(hi.y);
    f[6] = (short)f2bf(hi.z); f[7] = (short)f2bf(hi.w);
    return f;
}

// ---------------- Kernel A: partial QK^T via bf16 MFMA (R8 structure) ----
// grid (ch=kchunks FASTEST, bn=64), 1024 threads = 16 waves.
// Per phase (256 k): every thread bursts 8x float4 (64B Q + 64B K), bf16-pack
// into XOR-swizzled LDS [64][256] tiles, one barrier, 8 MFMA k-steps
// (wave w owns 16x16 output tile (w>>2, w&3)).
// partial[ch][bn][p][q]
__global__ __launch_bounds__(1024) void qk_mfma_kernel(
    const float* __restrict__ Q, const float* __restrict__ K,
    float* __restrict__ partial, int clen)
{
    __shared__ unsigned short Qs[64 * 256];   // 32 KiB bf16 [row][k]
    __shared__ unsigned short Ks[64 * 256];   // 32 KiB

    const int ch   = blockIdx.x;        // FASTEST: concurrent blocks share rows
    const int bn   = blockIdx.y;
    const int tid  = threadIdx.x;
    const int w    = tid >> 6;
    const int lane = tid & 63;
    const int wr   = w >> 2;            // p-tile 0..3
    const int wc   = w & 3;             // q-tile 0..3
    const int frow = lane & 15;
    const int kg   = lane >> 4;         // 0..3

    const float* Qb = Q + (size_t)bn * 64 * 8192 + (size_t)ch * clen;
    const float* Kb = K + (size_t)bn * 64 * 8192 + (size_t)ch * clen;

    const int srow = tid >> 4;          // staged row 0..63
    const int sc   = (tid & 15) * 16;   // float col base: thread covers 64B
    const int nph  = clen >> 8;         // phases of 256 k (1 when kchunks=32)

    f32x4 acc = (f32x4)(0.f);
    const int arow = wr * 16 + frow;
    const int brow = wc * 16 + frow;

    #pragma unroll 1
    for (int ph = 0; ph < nph; ++ph) {
        const float4* qp = (const float4*)(Qb + (size_t)srow * 8192 + ph * 256 + sc);
        const float4* kp = (const float4*)(Kb + (size_t)srow * 8192 + ph * 256 + sc);
        const float4 q0 = qp[0], q1 = qp[1], q2 = qp[2], q3 = qp[3];
        const float4 k0 = kp[0], k1 = kp[1], k2 = kp[2], k3 = kp[3];
        if (ph) __syncthreads();        // protect prior phase's LDS reads
        // 16B-slot swizzle: slot' = slot ^ (row&7)  (32 slots of 16B per row)
        const int sl0 = ((tid & 15) * 2    ) ^ (srow & 7);
        const int sl1 = ((tid & 15) * 2 + 1) ^ (srow & 7);
        *(bf16x8*)(Qs + srow * 256 + sl0 * 8) = pack8(q0, q1);
        *(bf16x8*)(Qs + srow * 256 + sl1 * 8) = pack8(q2, q3);
        *(bf16x8*)(Ks + srow * 256 + sl0 * 8) = pack8(k0, k1);
        *(bf16x8*)(Ks + srow * 256 + sl1 * 8) = pack8(k2, k3);
        __syncthreads();
        #pragma unroll
        for (int ks = 0; ks < 8; ++ks) {
            const bf16x8 a = *(const bf16x8*)(Qs + arow * 256 +
                                (((ks * 4 + kg) ^ (arow & 7)) * 8));
            const bf16x8 b = *(const bf16x8*)(Ks + brow * 256 +
                                (((ks * 4 + kg) ^ (brow & 7)) * 8));
            acc = __builtin_amdgcn_mfma_f32_16x16x32_bf16(a, b, acc, 0, 0, 0);
        }
    }

    // D layout: col = lane&15 (q), row = kg*4 + r (p)
    float* pb = partial + ((size_t)ch * 64 + bn) * 4096;
    const int p0 = wr * 16 + kg * 4;
    const int q0 = wc * 16 + frow;
    #pragma unroll
    for (int r = 0; r < 4; ++r)
        pb[(size_t)(p0 + r) * 64 + q0] = acc[r];
}

// ---------------- Kernel B: reduce partials + softmax (unchanged) ----------------
__global__ __launch_bounds__(256) void softmax_kernel(
    float* __restrict__ ws, const unsigned char* __restrict__ mask, int kchunks)
{
    const int row  = blockIdx.x * 4 + (threadIdx.x >> 6);
    const int q    = threadIdx.x & 63;
    float s = 0.f;
    for (int c = 0; c < kchunks; ++c)
        s += ws[((size_t)c * 4096 + row) * 64 + q];
    s *= (1.0f / 1024.0f);
    const int b = row >> 9;
    if (mask[b * 64 + q]) s = -__builtin_inff();
    float m = s;
    #pragma unroll
    for (int off = 32; off; off >>= 1) m = fmaxf(m, __shfl_xor(m, off));
    const float e = __expf(s - m);
    float sum = e;
    #pragma unroll
    for (int off = 32; off; off >>= 1) sum += __shfl_xor(sum, off);
    ws[(size_t)row * 64 + q] = e / sum;
}

// ---------------- Kernel C: PV via bf16 MFMA (unchanged, proven) ----------------
__global__ __launch_bounds__(512, 2) void pv_mfma_kernel(
    const float* __restrict__ V, const float* __restrict__ attn,
    float* __restrict__ out)
{
    __shared__ unsigned char smem[65536];   // phase 1: vt[8][64][64] bf16; phase 2: ob fp32

    const int b     = blockIdx.y;
    const int chunk = blockIdx.x;
    const int tid   = threadIdx.x;
    const int w     = tid >> 6;           // wave = n
    const int lane  = tid & 63;

    const float* Vb = V    + (size_t)(b * 8 + w) * 64 * 8192 + (size_t)chunk * 64;
    const float* Ab = attn + (size_t)(b * 8 + w) * 4096;

    unsigned short* vtn = (unsigned short*)smem + w * 4096;   // this wave's V^T tile

    // ---- stage V chunk -> LDS transposed bf16, swizzled ----
    const int c  = lane >> 2;
    const int qg = lane & 3;
    #pragma unroll
    for (int s = 0; s < 4; ++s) {
        const int q0 = s * 16 + qg * 4;
        const float4 r0 = *(const float4*)&Vb[(size_t)(q0 + 0) * 8192 + c * 4];
        const float4 r1 = *(const float4*)&Vb[(size_t)(q0 + 1) * 8192 + c * 4];
        const float4 r2 = *(const float4*)&Vb[(size_t)(q0 + 2) * 8192 + c * 4];
        const float4 r3 = *(const float4*)&Vb[(size_t)(q0 + 3) * 8192 + c * 4];
        const float v0[4] = {r0.x, r0.y, r0.z, r0.w};
        const float v1[4] = {r1.x, r1.y, r1.z, r1.w};
        const float v2[4] = {r2.x, r2.y, r2.z, r2.w};
        const float v3[4] = {r3.x, r3.y, r3.z, r3.w};
        #pragma unroll
        for (int cc = 0; cc < 4; ++cc) {
            const int row = c * 4 + cc;       // xc within chunk
            shortx4 pk;
            pk.x = (short)f2bf(v0[cc]);
            pk.y = (short)f2bf(v1[cc]);
            pk.z = (short)f2bf(v2[cc]);
            pk.w = (short)f2bf(v3[cc]);
            const int soff = row * 64 + (q0 ^ ((row & 7) << 3) ^ (((row >> 3) & 3) << 4));
            *(shortx4*)(vtn + soff) = pk;
        }
    }

    // ---- A fragments: attn rows, bf16 ----
    const int arow = lane & 15;
    const int q0a  = (lane >> 4) * 8;
    bf16x8 afrag[4][2];
    #pragma unroll
    for (int mt = 0; mt < 4; ++mt) {
        #pragma unroll
        for (int ks = 0; ks < 2; ++ks) {
            const float* ap = Ab + (mt * 16 + arow) * 64 + ks * 32 + q0a;
            const float4 lo = *(const float4*)ap;
            const float4 hi = *(const float4*)(ap + 4);
            afrag[mt][ks] = pack8(lo, hi);
        }
    }

    // ---- MFMA compute ----
    f32x4 acc[4][4];
    #pragma unroll
    for (int mt = 0; mt < 4; ++mt)
        #pragma unroll
        for (int nt = 0; nt < 4; ++nt)
            acc[mt][nt] = (f32x4)(0.f);

    const int bcol = lane & 15;
    const int q0b  = (lane >> 4) * 8;
    #pragma unroll
    for (int nt = 0; nt < 4; ++nt) {
        bf16x8 bfr[2];
        #pragma unroll
        for (int ks = 0; ks < 2; ++ks) {
            const int row  = nt * 16 + bcol;
            const int q0   = ks * 32 + q0b;
            const int soff = row * 64 + (q0 ^ ((row & 7) << 3) ^ (((row >> 3) & 3) << 4));
            bfr[ks] = *(const bf16x8*)(vtn + soff);
        }
        #pragma unroll
        for (int ks = 0; ks < 2; ++ks)
            #pragma unroll
            for (int mt = 0; mt < 4; ++mt)
                acc[mt][nt] = __builtin_amdgcn_mfma_f32_16x16x32_bf16(
                    afrag[mt][ks], bfr[ks], acc[mt][nt], 0, 0, 0);
    }

    // ---- store: D frags -> LDS transpose -> coalesced float4 stores ----
    float* ob = (float*)smem;          // [16 p][64 xc][9 (8n + pad)]
    const int pq = lane >> 4;
    const int pl = tid >> 5;           // 0..15 : p-row for store phase
    const int g  = tid & 31;
    #pragma unroll
    for (int mt = 0; mt < 4; ++mt) {
        __syncthreads();
        #pragma unroll
        for (int nt = 0; nt < 4; ++nt)
            #pragma unroll
            for (int r = 0; r < 4; ++r) {
                const int prow = pq * 4 + r;
                const int xc   = nt * 16 + (lane & 15);
                ob[prow * 576 + xc * 9 + w] = acc[mt][nt][r];
            }
        __syncthreads();
        float* orow = out + (size_t)b * 4194304 + (size_t)(mt * 16 + pl) * 65536
                          + (size_t)chunk * 512;
        #pragma unroll
        for (int u = 0; u < 4; ++u) {
            const int f0 = g * 4 + u * 128;
            float4 vv;
            vv.x = ob[pl * 576 + ((f0 + 0) >> 3) * 9 + ((f0 + 0) & 7)];
            vv.y = ob[pl * 576 + ((f0 + 1) >> 3) * 9 + ((f0 + 1) & 7)];
            vv.z = ob[pl * 576 + ((f0 + 2) >> 3) * 9 + ((f0 + 2) & 7)];
            vv.w = ob[pl * 576 + ((f0 + 3) >> 3) * 9 + ((f0 + 3) & 7)];
            *(float4*)&orow[f0] = vv;
        }
    }
}

extern "C" void kernel_launch(void* const* d_in, const int* in_sizes, int n_in,
                              void* d_out, int out_size, void* d_ws, size_t ws_size,
                              hipStream_t stream)
{
    const float* Q = (const float*)d_in[0];
    const float* K = (const float*)d_in[1];
    const float* V = (const float*)d_in[2];
    const unsigned char* mask = (const unsigned char*)d_in[3];
    float* out = (float*)d_out;
    float* ws  = (float*)d_ws;

    // partial needs kchunks * 4096 * 64 * 4 bytes = kchunks MiB
    int kchunks = 32;
    while (kchunks > 1 &&
           (size_t)kchunks * 4096 * 64 * sizeof(float) > ws_size)
        kchunks >>= 1;
    const int clen = 8192 / kchunks;

    // ch is blockIdx.x (fastest) -> concurrent blocks read adjacent 1KB
    // column-windows of the SAME rows -> dense cross-block DRAM streams.
    qk_mfma_kernel<<<dim3(kchunks, 64), 1024, 0, stream>>>(Q, K, ws, clen);
    softmax_kernel<<<1024, 256, 0, stream>>>(ws, mask, kchunks);
    pv_mfma_kernel<<<dim3(128, 8), 512, 0, stream>>>(V, ws, out);
}